// Round 4
// baseline (946.456 us; speedup 1.0000x reference)
//
#include <hip/hip_runtime.h>
#include <stdint.h>

// ---------------------------------------------------------------------------
// MoE top-2 FFN on gfx950: fp32 gating (exact expert selection), fp16 MFMA
// grouped GEMMs, routed ybuf + gather combine.
// R6->R7: ffn1 ported to the 256x256 8-wave deep-pipelined schedule
// (T2 swizzle kept, T3 phase split, T4 counted vmcnt(4) never 0 in-loop,
// T5 setprio around MFMA clusters). ffn1 was structure-bound at the m97
// ceiling (MfmaUtil 35%, HBM 15%). Experts stay 128-padded; 256-tiles with
// row-limit guard on the straddle tile. ffn2 remains 128x128.
// ---------------------------------------------------------------------------

typedef _Float16 f16;
typedef f16  f16x8 __attribute__((ext_vector_type(8)));
typedef f16  f16x4 __attribute__((ext_vector_type(4)));
typedef float fx4  __attribute__((ext_vector_type(4)));

#define NEXP 8
#define CHUNK 1024          // assignments per routing block
// meta layout (ints):
#define M_PART 0            // [32*8] per-block expert counts
#define M_OFF  256          // [9] expert slot offsets (padded 128)
#define M_BB   272          // [32*8] per-block scatter bases
#define M_TE   528          // [<=512] 128-tile -> expert (ffn2)
#define M_TR   1040         // [<=512] 128-tile -> first slot row
#define M_TE2  1552         // [<=144] 256-tile -> expert (ffn1)
#define M_TR2  1696         // [<=144] 256-tile -> first slot row
#define M_RL2  1840         // [<=144] 256-tile -> valid row limit (128|256)

__device__ __forceinline__ void gload_lds16(const f16* g, f16* l) {
  // global->LDS DMA, 16 B/lane. LDS dest is wave-uniform base + lane*16.
  __builtin_amdgcn_global_load_lds(
      (const __attribute__((address_space(1))) void*)g,
      (__attribute__((address_space(3))) void*)l, 16, 0, 0);
}

// ---------------- w1/w3 -> interleaved fp16 slice  [E][2*FS][D] -------------
__global__ __launch_bounds__(256) void cvt_w13_kernel(const float* __restrict__ w1,
                                                      const float* __restrict__ w3,
                                                      f16* __restrict__ w13,
                                                      int D, int F, int FS, int fbase) {
  long i = (long)blockIdx.x * 256 + threadIdx.x;          // float4 id
  long n4 = (long)NEXP * 2 * FS * (D / 4);
  if (i >= n4) return;
  int d4 = (int)(i % (D / 4));
  int rr = (int)((i / (D / 4)) % (2 * FS));
  int e  = (int)(i / ((long)(D / 4) * 2 * FS));
  const float* src = ((rr & 1) ? w3 : w1) + ((long)e * F + fbase + (rr >> 1)) * D + d4 * 4;
  float4 v = *(const float4*)src;
  f16x4 o = {(f16)v.x, (f16)v.y, (f16)v.z, (f16)v.w};
  *(f16x4*)(w13 + i * 4) = o;
}

// ---------------- w2 -> fp16 k-slice  [E][D][FS] ---------------------------
__global__ __launch_bounds__(256) void cvt_w2_kernel(const float* __restrict__ w2,
                                                     f16* __restrict__ w2s,
                                                     int D, int F, int FS, int fbase) {
  long i = (long)blockIdx.x * 256 + threadIdx.x;          // float4 id
  long n4 = (long)NEXP * D * (FS / 4);
  if (i >= n4) return;
  int k4 = (int)(i % (FS / 4));
  int d  = (int)((i / (FS / 4)) % D);
  int e  = (int)(i / ((long)(FS / 4) * D));
  const float* src = w2 + ((long)e * D + d) * F + fbase + k4 * 4;
  float4 v = *(const float4*)src;
  f16x4 o = {(f16)v.x, (f16)v.y, (f16)v.z, (f16)v.w};
  *(f16x4*)(w2s + i * 4) = o;
}

// ---------------- gating: fp32 logits, top-2, x->fp16 (no atomics) ---------
__global__ __launch_bounds__(256) void gate_kernel(const float* __restrict__ x,
                                                   const float* __restrict__ gw,
                                                   f16* __restrict__ xb,
                                                   int* __restrict__ topk_id,
                                                   float* __restrict__ topk_w,
                                                   int D) {
  const int lane = threadIdx.x & 63;
  const int wave = threadIdx.x >> 6;
  const long tok = (long)blockIdx.x * 4 + wave;
  const float* xrow = x + tok * D;

  float part[NEXP];
#pragma unroll
  for (int e = 0; e < NEXP; ++e) part[e] = 0.f;

  for (int c = 0; c < D / 256; ++c) {
    int idx = (c * 64 + lane) * 4;
    float4 xv = *(const float4*)(xrow + idx);
    f16x4 o = {(f16)xv.x, (f16)xv.y, (f16)xv.z, (f16)xv.w};
    *(f16x4*)(xb + tok * D + idx) = o;
#pragma unroll
    for (int e = 0; e < NEXP; ++e) {
      float4 gv = *(const float4*)(gw + (long)e * D + idx);
      part[e] += xv.x * gv.x + xv.y * gv.y + xv.z * gv.z + xv.w * gv.w;
    }
  }
#pragma unroll
  for (int e = 0; e < NEXP; ++e)
    for (int off = 32; off; off >>= 1) part[e] += __shfl_xor(part[e], off);

  // top-2, lowest index wins ties (matches lax.top_k stable ordering)
  int i0 = 0; float m0 = part[0];
#pragma unroll
  for (int e = 1; e < NEXP; ++e) if (part[e] > m0) { m0 = part[e]; i0 = e; }
  int i1 = (i0 == 0) ? 1 : 0; float m1 = part[i1];
#pragma unroll
  for (int e = 0; e < NEXP; ++e)
    if (e != i0 && e != ((i0 == 0) ? 1 : 0) && part[e] > m1) { m1 = part[e]; i1 = e; }

  if (lane == 0) {
    // renormalized top-2 softmax == sigmoid of logit difference (fp32 exact)
    float w0 = 1.f / (1.f + expf(m1 - m0));
    float w1 = 1.f / (1.f + expf(m0 - m1));
    topk_id[2 * tok] = i0; topk_id[2 * tok + 1] = i1;
    topk_w[2 * tok] = w0;  topk_w[2 * tok + 1] = w1;
  }
}

// ---------------- per-block expert histogram (LDS, no global contention) ----
__global__ __launch_bounds__(256) void count_kernel(const int* __restrict__ topk_id,
                                                    int* __restrict__ meta, int n2) {
  __shared__ int h[NEXP];
  const int t = threadIdx.x;
  if (t < NEXP) h[t] = 0;
  __syncthreads();
  const int lo = blockIdx.x * CHUNK;
  const int hi = min(n2, lo + CHUNK);
  for (int i = lo + t; i < hi; i += 256) atomicAdd(&h[topk_id[i]], 1);
  __syncthreads();
  if (t < NEXP) meta[M_PART + blockIdx.x * NEXP + t] = h[t];
}

// ---------------- offsets + both tile maps + bases + pad fill --------------
__global__ void setup_kernel(int* __restrict__ meta, int* __restrict__ routed_token,
                             float* __restrict__ routed_w, int MT, int MT2, int CB) {
  __shared__ int s_off[NEXP], s_cnt[NEXP], s_tot;
  const int t = threadIdx.x;
  if (t == 0) {
    int cnt[NEXP];
    for (int e = 0; e < NEXP; ++e) cnt[e] = 0;
    for (int b = 0; b < CB; ++b)
      for (int e = 0; e < NEXP; ++e) cnt[e] += meta[M_PART + b * NEXP + e];
    int off = 0, tt = 0, t2 = 0;
    for (int e = 0; e < NEXP; ++e) {
      s_cnt[e] = cnt[e]; s_off[e] = off;
      meta[M_OFF + e] = off;
      int p = (cnt[e] + 127) & ~127;
      for (int i = 0; i < (p >> 7); ++i) {
        meta[M_TE + tt] = e; meta[M_TR + tt] = off + i * 128; ++tt;
      }
      int full = p >> 8;
      for (int i = 0; i < full; ++i) {
        meta[M_TE2 + t2] = e; meta[M_TR2 + t2] = off + i * 256; meta[M_RL2 + t2] = 256; ++t2;
      }
      if (p & 255) {  // odd number of 128-tiles -> straddle tile, 128 valid rows
        meta[M_TE2 + t2] = e; meta[M_TR2 + t2] = off + full * 256; meta[M_RL2 + t2] = 128; ++t2;
      }
      off += p;
    }
    meta[M_OFF + NEXP] = off; s_tot = off;
    for (; tt < MT; ++tt) meta[M_TE + tt] = -1;
    for (; t2 < MT2; ++t2) meta[M_TE2 + t2] = -1;
    // exclusive per-block scatter bases
    for (int e = 0; e < NEXP; ++e) {
      int run = meta[M_OFF + e];
      for (int b = 0; b < CB; ++b) {
        meta[M_BB + b * NEXP + e] = run;
        run += meta[M_PART + b * NEXP + e];
      }
    }
  }
  __syncthreads();
  for (int e = 0; e < NEXP; ++e) {
    int start = s_off[e] + s_cnt[e];
    int end = s_off[e] + ((s_cnt[e] + 127) & ~127);
    for (int i = start + t; i < end; i += blockDim.x) {
      routed_token[i] = 0;      // pad rows -> token 0 (finite garbage)
      routed_w[i] = 0.f;        // zero gate weight kills pad contribution
    }
  }
  // tail slack for straddle-tile over-reads (rows [tot, tot+256))
  for (int i = s_tot + t; i < s_tot + 256; i += blockDim.x) {
    routed_token[i] = 0; routed_w[i] = 0.f;
  }
}

// ---------------- scatter tokens into per-expert slots (LDS cursors) -------
__global__ __launch_bounds__(256) void scatter_kernel(const int* __restrict__ topk_id,
                                                      const float* __restrict__ topk_w,
                                                      const int* __restrict__ meta,
                                                      int* __restrict__ routed_token,
                                                      float* __restrict__ routed_w,
                                                      int* __restrict__ slot_pos,
                                                      int n2) {
  __shared__ int cur[NEXP];
  const int t = threadIdx.x;
  if (t < NEXP) cur[t] = meta[M_BB + blockIdx.x * NEXP + t];
  __syncthreads();
  const int lo = blockIdx.x * CHUNK;
  const int hi = min(n2, lo + CHUNK);
  for (int i = lo + t; i < hi; i += 256) {
    int e = topk_id[i];
    int pos = atomicAdd(&cur[e], 1);
    routed_token[pos] = i >> 1;
    routed_w[pos] = topk_w[i];
    slot_pos[i] = pos;
  }
}

// ---------------- GEMM1: 256x256 8-wave deep-pipelined -------------------
// Tile: 256 token-rows x 256 interleaved weight-rows (2j=w1, 2j+1=w3).
// 8 waves 2M x 4N (per-wave 128x64). BK=64, dbuf LDS (128 KiB), 4 phases
// per K-tile: {p1: rdA(mh0)+rdB(nh0) | stage A(k+1)h0 | MFMA Q00}
//             {p2: rdB(nh1)          | stage A(k+1)h1 | MFMA Q01}
//             {p3: rdA(mh1)          | stage B(k+2)h0 | MFMA Q11}
//             {p4:                   | stage B(k+2)h1 | MFMA Q10 | vmcnt(4)}
// Hazards: buf B released after p2 barrier, buf A after p3 barrier; each
// prefetch targets only released regions. vmcnt(4) = 2 half-tiles in flight,
// never drained to 0 in the loop.
#define STAGE_A(kk, h) do { int cc = (kk) & 1;                                  \
    f16* d_ = smem + cc * 16384 + ((h) * 1024 + (t & ~63)) * 8;                 \
    gload_lds16(aSrc[h][0] + (long)(kk) * 64, d_);                              \
    gload_lds16(aSrc[h][1] + (long)(kk) * 64, d_ + 4096); } while (0)
#define STAGE_B(kk, h) do { int cc = (kk) & 1;                                  \
    f16* d_ = smem + 32768 + cc * 16384 + ((h) * 1024 + (t & ~63)) * 8;         \
    gload_lds16(bSrc[h][0] + (long)(kk) * 64, d_);                              \
    gload_lds16(bSrc[h][1] + (long)(kk) * 64, d_ + 4096); } while (0)
#define READ_A(MH) do {                                                         \
    _Pragma("unroll")                                                           \
    for (int mf = 0; mf < 4; ++mf) {                                            \
      _Pragma("unroll")                                                         \
      for (int ks = 0; ks < 2; ++ks) {                                          \
        int row = wr * 128 + (MH) * 64 + mf * 16 + rA;                          \
        int kg = ks * 4 + kgb;                                                  \
        aF[mf][ks] = *(const f16x8*)(Ab + row * 64 + ((kg ^ (row & 7)) * 8));   \
      } } } while (0)
#define READ_B(NH) do {                                                         \
    _Pragma("unroll")                                                           \
    for (int nf = 0; nf < 2; ++nf) {                                            \
      _Pragma("unroll")                                                         \
      for (int ks = 0; ks < 2; ++ks) {                                          \
        int row = wc * 64 + ((NH) * 2 + nf) * 16 + rA;                          \
        int kg = ks * 4 + kgb;                                                  \
        bF[(NH) * 2 + nf][ks] = *(const f16x8*)(Bb + row * 64 + ((kg ^ (row & 7)) * 8)); \
      } } } while (0)
#define MFMA_Q(MH, NH) do {                                                     \
    _Pragma("unroll")                                                           \
    for (int mf = 0; mf < 4; ++mf) {                                            \
      _Pragma("unroll")                                                         \
      for (int nf = 0; nf < 2; ++nf) {                                          \
        _Pragma("unroll")                                                       \
        for (int ks = 0; ks < 2; ++ks) {                                        \
          acc[(MH) * 4 + mf][(NH) * 2 + nf] = __builtin_amdgcn_mfma_f32_16x16x32_f16( \
              aF[mf][ks], bF[(NH) * 2 + nf][ks], acc[(MH) * 4 + mf][(NH) * 2 + nf], 0, 0, 0); \
        } } } } while (0)
#define PH_MID() do { __builtin_amdgcn_s_barrier();                             \
    asm volatile("s_waitcnt lgkmcnt(0)" ::: "memory");                          \
    __builtin_amdgcn_sched_barrier(0);                                          \
    __builtin_amdgcn_s_setprio(1); } while (0)
#define PH_END() do { __builtin_amdgcn_s_setprio(0);                            \
    __builtin_amdgcn_s_barrier();                                               \
    __builtin_amdgcn_sched_barrier(0); } while (0)

__global__ __launch_bounds__(512, 2) void ffn1_kernel(const f16* __restrict__ xb,
                                                      const f16* __restrict__ w13,
                                                      const int* __restrict__ routed_token,
                                                      const float* __restrict__ routed_w,
                                                      const int* __restrict__ meta,
                                                      f16* __restrict__ hbuf,
                                                      int D, int FS) {
  const int e = meta[M_TE2 + blockIdx.y];
  if (e < 0) return;
  const int r0   = meta[M_TR2 + blockIdx.y];
  const int rlim = meta[M_RL2 + blockIdx.y];
  const int f0 = blockIdx.x * 128;              // f-cols per block

  __shared__ __align__(16) f16 smem[4 * 256 * 64];   // 128 KiB: A0|A1|B0|B1
  __shared__ float s_w[256];

  const int t = threadIdx.x;
  const int lane = t & 63;
  const int wave = t >> 6;        // 0..7
  const int wr = wave >> 2;       // 0..1 (M)
  const int wc = wave & 3;        // 0..3 (N)
  const int rA = lane & 15;
  const int kgb = lane >> 4;

  if (t < 256) s_w[t] = routed_w[r0 + t];

  // staging sources: half h in {0,1}, granule-call q in {0,1}
  // granule gi = q*512 + t -> row r = h*128 + (gi>>3), col-gran (gi&7)^(r&7)
  const f16* aSrc[2][2];
  const f16* bSrc[2][2];
#pragma unroll
  for (int h = 0; h < 2; ++h)
#pragma unroll
    for (int q = 0; q < 2; ++q) {
      int gi = q * 512 + t;
      int r = h * 128 + (gi >> 3);
      int sg = (gi & 7) ^ (r & 7);
      int tok = routed_token[r0 + r];
      aSrc[h][q] = xb + (long)tok * D + sg * 8;
      bSrc[h][q] = w13 + ((long)e * 2 * FS + 2 * f0 + r) * D + sg * 8;
    }

  fx4 acc[8][4];
#pragma unroll
  for (int i = 0; i < 8; ++i)
#pragma unroll
    for (int j = 0; j < 4; ++j) acc[i][j] = (fx4){0.f, 0.f, 0.f, 0.f};

  const int NT = D >> 6;          // K-tiles (>=2)

  // prologue: B(0), A(0), B(1) in flight; gate so B(0),A(0) landed
  STAGE_B(0, 0); STAGE_B(0, 1);
  STAGE_A(0, 0); STAGE_A(0, 1);
  STAGE_B(1, 0); STAGE_B(1, 1);
  asm volatile("s_waitcnt vmcnt(4)" ::: "memory");
  __builtin_amdgcn_s_barrier();
  __builtin_amdgcn_sched_barrier(0);

  for (int k = 0; k < NT; ++k) {
    const int c = k & 1;
    const f16* Ab = smem + c * 16384;
    const f16* Bb = smem + 32768 + c * 16384;
    f16x8 aF[4][2], bF[4][2];
    // ---- p1
    READ_A(0); READ_B(0);
    if (k + 1 < NT) STAGE_A(k + 1, 0);
    PH_MID(); MFMA_Q(0, 0); PH_END();
    // ---- p2
    READ_B(1);
    if (k + 1 < NT) STAGE_A(k + 1, 1);
    PH_MID(); MFMA_Q(0, 1); PH_END();
    // ---- p3
    READ_A(1);
    if (k + 2 < NT) STAGE_B(k + 2, 0);
    PH_MID(); MFMA_Q(1, 1); PH_END();
    // ---- p4 (register-only MFMA; K-tile gate, counted — never 0)
    if (k + 2 < NT) STAGE_B(k + 2, 1);
    __builtin_amdgcn_s_setprio(1);
    MFMA_Q(1, 0);
    __builtin_amdgcn_s_setprio(0);
    asm volatile("s_waitcnt vmcnt(4)" ::: "memory");
    __builtin_amdgcn_s_barrier();
    __builtin_amdgcn_sched_barrier(0);
  }

  // epilogue: dedup even(w1)/odd(w3) silu, scale by gate w, LDS transpose.
  f16* sH = smem;                       // [256][136] = 69.6 KB
  const int odd = lane & 1;
  const int j = (lane & 15) >> 1;
#pragma unroll
  for (int mf = 0; mf < 8; ++mf)
#pragma unroll
    for (int nfp = 0; nfp < 4; nfp += 2)
#pragma unroll
      for (int rg = 0; rg < 4; ++rg) {
        float v0 = acc[mf][nfp][rg];
        float v1 = acc[mf][nfp + 1][rg];
        float t0 = __shfl_xor(v0, 1);
        float t1 = __shfl_xor(v1, 1);
        float c1 = odd ? t1 : v0;
        float c3 = odd ? v1 : t0;
        float ex = __expf(-c1);
        float hv = c1 * c3 * __builtin_amdgcn_rcpf(1.f + ex);
        int ml = wr * 128 + mf * 16 + (lane >> 4) * 4 + rg;
        int fl = wc * 32 + (nfp + odd) * 8 + j;
        sH[ml * 136 + fl] = (f16)(hv * s_w[ml]);
      }
  __syncthreads();
#pragma unroll
  for (int qq = 0; qq < 8; ++qq) {
    int gi = qq * 512 + t;              // 4096 granules = 256 rows x 16
    int r = gi >> 4, gc = gi & 15;
    if (r < rlim)
      *(f16x8*)(hbuf + (long)(r0 + r) * FS + f0 + gc * 8) =
          *(const f16x8*)(sH + r * 136 + gc * 8);
  }
}

// ---------------- GEMM2: y[slot] = (h @ w2^T) slice (h pre-weighted) -------
// Grid: (D/128, MT) — x = d-slice (fastest) for hbuf A-tile L2 reuse.
__global__ __launch_bounds__(256) void ffn2_kernel(const f16* __restrict__ hbuf,
                                                   const f16* __restrict__ w2s,
                                                   const int* __restrict__ routed_token,
                                                   const int* __restrict__ meta,
                                                   float* __restrict__ out,
                                                   f16* __restrict__ ybuf,
                                                   int D, int FS) {
  const int e = meta[M_TE + blockIdx.y];
  if (e < 0) return;
  const int r0 = meta[M_TR + blockIdx.y];
  const int d0 = blockIdx.x * 128;

  __shared__ __align__(16) f16 smem[128 * 136];
  __shared__ int s_tok[128];
  f16* sA = smem;
  f16* sB = smem + 128 * 64;

  const int t = threadIdx.x;
  const int lane = t & 63;
  const int wave = t >> 6;
  const int wm = (wave & 1) * 64;
  const int wn = (wave >> 1) * 64;

  if (!ybuf && t < 128) s_tok[t] = routed_token[r0 + t];

  const int rb = t >> 3;
  const int sgg = (t & 7) ^ (rb & 7);
  const f16* aptr[4];
  const f16* bptr[4];
#pragma unroll
  for (int q = 0; q < 4; ++q) {
    int r = q * 32 + rb;
    aptr[q] = hbuf + (long)(r0 + r) * FS + sgg * 8;
    bptr[q] = w2s + ((long)e * D + d0 + r) * FS + sgg * 8;
  }
  f16* ldsA[4]; f16* ldsB[4];
#pragma unroll
  for (int q = 0; q < 4; ++q) {
    int gbase = (q * 256 + (t & ~63)) * 8;
    ldsA[q] = sA + gbase;
    ldsB[q] = sB + gbase;
  }

  fx4 acc[4][4];
#pragma unroll
  for (int i = 0; i < 4; ++i)
#pragma unroll
    for (int j = 0; j < 4; ++j) acc[i][j] = (fx4){0.f, 0.f, 0.f, 0.f};

  for (int kc = 0; kc < FS; kc += 64) {
#pragma unroll
    for (int q = 0; q < 4; ++q) {
      gload_lds16(aptr[q] + kc, ldsA[q]);
      gload_lds16(bptr[q] + kc, ldsB[q]);
    }
    __syncthreads();
#pragma unroll
    for (int ks = 0; ks < 2; ++ks) {
      f16x8 aF[4], bF[4];
      const int kg = ks * 4 + (lane >> 4);
#pragma unroll
      for (int mf = 0; mf < 4; ++mf) {
        int row = wm + mf * 16 + (lane & 15);
        aF[mf] = *(const f16x8*)(sA + row * 64 + (kg ^ (row & 7)) * 8);
      }
#pragma unroll
      for (int nf = 0; nf < 4; ++nf) {
        int row = wn + nf * 16 + (lane & 15);
        bF[nf] = *(const f16x8*)(sB + row * 64 + (kg ^ (row & 7)) * 8);
      }
#pragma unroll
      for (int mf = 0; mf < 4; ++mf)
#pragma unroll
        for (int nf = 0; nf < 4; ++nf)
          acc[mf][nf] = __builtin_amdgcn_mfma_f32_16x16x32_f16(aF[mf], bF[nf], acc[mf][nf], 0, 0, 0);
    }
    __syncthreads();
  }

  if (ybuf) {
    f16* sH = smem;                     // [128][136]
#pragma unroll
    for (int mf = 0; mf < 4; ++mf)
#pragma unroll
      for (int nf = 0; nf < 4; ++nf)
#pragma unroll
        for (int rg = 0; rg < 4; ++rg) {
          int row = wm + mf * 16 + (lane >> 4) * 4 + rg;
          int col = wn + nf * 16 + (lane & 15);
          sH[row * 136 + col] = (f16)acc[mf][nf][rg];
        }
    __syncthreads();
#pragma unroll
    for (int q = 0; q < 8; ++q) {
      int gi = q * 256 + t;
      int r = gi >> 4, c = (gi & 15) * 8;
      *(f16x8*)(ybuf + (long)(r0 + r) * D + d0 + c) = *(const f16x8*)(sH + r * 136 + c);
    }
  } else {
#pragma unroll
    for (int mf = 0; mf < 4; ++mf) {
#pragma unroll
      for (int rg = 0; rg < 4; ++rg) {
        int row = wm + mf * 16 + (lane >> 4) * 4 + rg;
        long obase = (long)s_tok[row] * D + d0;
#pragma unroll
        for (int nf = 0; nf < 4; ++nf) {
          int nl = wn + nf * 16 + (lane & 15);
          atomicAdd(out + obase + nl, acc[mf][nf][rg]);
        }
      }
    }
  }
}

// ---------------- combine: out[tok] = y[slot0] + y[slot1] ------------------
__global__ __launch_bounds__(256) void combine_kernel(const f16* __restrict__ y,
                                                      const int* __restrict__ slot_pos,
                                                      float* __restrict__ out, int D) {
  const long tok = blockIdx.x;
  const int g = threadIdx.x * 8;
  const int p0 = slot_pos[2 * tok];
  const int p1 = slot_pos[2 * tok + 1];
  f16x8 a = *(const f16x8*)(y + (long)p0 * D + g);
  f16x8 b = *(const f16x8*)(y + (long)p1 * D + g);
  float* op = out + tok * D + g;
  float4 o0 = {(float)a[0] + (float)b[0], (float)a[1] + (float)b[1],
               (float)a[2] + (float)b[2], (float)a[3] + (float)b[3]};
  float4 o1 = {(float)a[4] + (float)b[4], (float)a[5] + (float)b[5],
               (float)a[6] + (float)b[6], (float)a[7] + (float)b[7]};
  *(float4*)op = o0;
  *(float4*)(op + 4) = o1;
}

// ---------------------------------------------------------------------------
extern "C" void kernel_launch(void* const* d_in, const int* in_sizes, int n_in,
                              void* d_out, int out_size, void* d_ws, size_t ws_size,
                              hipStream_t stream) {
  const float* x  = (const float*)d_in[0];
  const float* gw = (const float*)d_in[1];
  const float* w1 = (const float*)d_in[2];
  const float* w2 = (const float*)d_in[3];
  const float* w3 = (const float*)d_in[4];
  float* out = (float*)d_out;

  const int E = NEXP;
  const int D = in_sizes[1] / E;                              // 1024
  const long N = (long)in_sizes[0] / D;                       // 16384
  const int F = (int)((long)in_sizes[2] / ((long)E * D));     // 2048
  const int MT = (int)(2 * N / 128 + E);                      // 264 128-tiles max
  const int MT2 = (int)(2 * N / 256 + E);                     // 136 256-tiles max
  const long RMAX = (long)MT * 128;
  const long out_bytes = (long)out_size * 4;
  const int n2 = (int)(2 * N);
  const int CB = (n2 + CHUNK - 1) / CHUNK;                    // 32 routing blocks

  char* base = (char*)d_ws;
  long off = 0;
  int*   meta         = (int*)(base + off); off += 8 * 1024;
  int*   topk_id      = (int*)(base + off); off += 2 * N * 4;
  float* topk_w       = (float*)(base + off); off += 2 * N * 4;
  int*   slot_pos     = (int*)(base + off); off += 2 * N * 4;
  int*   routed_token = (int*)(base + off); off += (RMAX + 256) * 4;
  float* routed_w     = (float*)(base + off); off += (RMAX + 256) * 4;
  off = (off + 255) & ~255L;
  const long small_end = off;

  const long w13_b = (long)E * 2 * F * D * 2;
  const long xb_b  = N * (long)D * 2;

  int S = 0; bool w13_in_dout = false; bool use_y = false;
  f16 *xb = nullptr, *w2s = nullptr, *hbuf = nullptr, *ybuf = nullptr, *w13 = nullptr;
  int FS = F;

  if (out_bytes >= w13_b) {
    const long w2s_b  = (long)E * D * F * 2;
    const long hbuf_b = RMAX * (long)F * 2;
    const long ybuf_b = RMAX * (long)D * 2;
    const long ovl_b  = (xb_b > ybuf_b) ? xb_b : ybuf_b;
    // Layout A: [small | w2s | hbuf | xb==ybuf overlay]  (xb dead after ffn1)
    if (small_end + w2s_b + hbuf_b + ovl_b <= (long)ws_size) {
      S = 1; w13_in_dout = true; use_y = true;
      long o = small_end;
      w2s  = (f16*)(base + o); o += w2s_b;
      hbuf = (f16*)(base + o); o += hbuf_b;
      xb   = (f16*)(base + o);
      ybuf = xb;                       // alias: ffn2 writes after ffn1's last xb read
      w13  = (f16*)d_out;
    } else if (small_end + xb_b + w2s_b + hbuf_b <= (long)ws_size) {
      S = 1; w13_in_dout = true;
      long o = small_end;
      xb   = (f16*)(base + o); o += xb_b;
      w2s  = (f16*)(base + o); o += w2s_b;
      hbuf = (f16*)(base + o);
      w13  = (f16*)d_out;
    }
  }
  if (!S) {
    const int cands[4] = {2, 4, 8, 16};
    for (int ci = 0; ci < 4 && !S; ++ci) {
      int s = cands[ci];
      if (F % (128 * s)) continue;
      long FSl = F / s;
      long w2s_b  = (long)E * D * FSl * 2;
      long hbuf_b = RMAX * FSl * 2;
      long w13s_b = (long)E * 2 * FSl * D * 2;
      if (small_end + xb_b + w2s_b + hbuf_b + w13s_b <= (long)ws_size) {
        S = s; FS = (int)FSl;
        long o = small_end;
        xb   = (f16*)(base + o); o += xb_b;
        w2s  = (f16*)(base + o); o += w2s_b;
        hbuf = (f16*)(base + o); o += hbuf_b;
        w13  = (f16*)(base + o);
      }
    }
  }
  if (!S) return;

  hipMemsetAsync(meta, 0, 8 * 1024, stream);
  gate_kernel<<<(int)(N / 4), 256, 0, stream>>>(x, gw, xb, topk_id, topk_w, D);
  count_kernel<<<CB, 256, 0, stream>>>(topk_id, meta, n2);
  setup_kernel<<<1, 256, 0, stream>>>(meta, routed_token, routed_w, MT, MT2, CB);
  scatter_kernel<<<CB, 256, 0, stream>>>(topk_id, topk_w, meta, routed_token, routed_w,
                                         slot_pos, n2);

  const long n13 = (long)E * 2 * FS * (D / 4);
  const long nw2 = (long)E * D * (FS / 4);
  const int b13 = (int)((n13 + 255) / 256);
  const int bw2 = (int)((nw2 + 255) / 256);

  if (w13_in_dout) {
    cvt_w13_kernel<<<b13, 256, 0, stream>>>(w1, w3, w13, D, F, FS, 0);
    cvt_w2_kernel<<<bw2, 256, 0, stream>>>(w2, w2s, D, F, FS, 0);
    dim3 g1(FS / 128, MT2);
    ffn1_kernel<<<g1, 512, 0, stream>>>(xb, w13, routed_token, routed_w, meta, hbuf, D, FS);
    dim3 g2(D / 128, MT);
    if (use_y) {
      ffn2_kernel<<<g2, 256, 0, stream>>>(hbuf, w2s, routed_token, meta, out, ybuf, D, FS);
      combine_kernel<<<(int)N, D / 8, 0, stream>>>(ybuf, slot_pos, out, D);
    } else {
      hipMemsetAsync(out, 0, out_bytes, stream);
      ffn2_kernel<<<g2, 256, 0, stream>>>(hbuf, w2s, routed_token, meta, out, nullptr, D, FS);
    }
  } else {
    hipMemsetAsync(out, 0, out_bytes, stream);
    for (int s = 0; s < S; ++s) {
      int fbase = s * FS;
      cvt_w13_kernel<<<b13, 256, 0, stream>>>(w1, w3, w13, D, F, FS, fbase);
      cvt_w2_kernel<<<bw2, 256, 0, stream>>>(w2, w2s, D, F, FS, fbase);
      dim3 g1(FS / 128, MT2);
      ffn1_kernel<<<g1, 512, 0, stream>>>(xb, w13, routed_token, routed_w, meta, hbuf, D, FS);
      dim3 g2(D / 128, MT);
      ffn2_kernel<<<g2, 256, 0, stream>>>(hbuf, w2s, routed_token, meta, out, nullptr, D, FS);
    }
  }
}

// Round 6
// 929.247 us; speedup vs baseline: 1.0185x; 1.0185x over previous
//
#include <hip/hip_runtime.h>
#include <stdint.h>

// ---------------------------------------------------------------------------
// MoE top-2 FFN on gfx950: fp32 gating (exact expert selection), fp16 MFMA
// grouped GEMMs, routed ybuf + gather combine.
// R8->R9: resubmit of R8 (container infra failed twice) with one real fix:
// tail vmcnt race. At k==NT-2 the B-prefetch is skipped, so the end-of-tile
// vmcnt(4) left the A(NT-1) stages in flight while iteration NT-1 read them.
// Now k==NT-2 drains with vmcnt(0) (once per block). Rest identical to R8:
// un-pinned phase schedule (no sched_barrier / no explicit lgkmcnt: ds_reads
// are compiler-tracked), raw s_barrier pairs, setprio around MFMA clusters,
// counted vmcnt(4) in steady state, bijective XCD-chunk swizzle on both
// GEMM grids.
// ---------------------------------------------------------------------------

typedef _Float16 f16;
typedef f16  f16x8 __attribute__((ext_vector_type(8)));
typedef f16  f16x4 __attribute__((ext_vector_type(4)));
typedef float fx4  __attribute__((ext_vector_type(4)));

#define NEXP 8
#define CHUNK 1024          // assignments per routing block
// meta layout (ints):
#define M_PART 0            // [32*8] per-block expert counts
#define M_OFF  256          // [9] expert slot offsets (padded 128)
#define M_BB   272          // [32*8] per-block scatter bases
#define M_TE   528          // [<=512] 128-tile -> expert (ffn2)
#define M_TR   1040         // [<=512] 128-tile -> first slot row
#define M_TE2  1552         // [<=144] 256-tile -> expert (ffn1)
#define M_TR2  1696         // [<=144] 256-tile -> first slot row
#define M_RL2  1840         // [<=144] 256-tile -> valid row limit (128|256)

__device__ __forceinline__ void gload_lds16(const f16* g, f16* l) {
  // global->LDS DMA, 16 B/lane. LDS dest is wave-uniform base + lane*16.
  __builtin_amdgcn_global_load_lds(
      (const __attribute__((address_space(1))) void*)g,
      (__attribute__((address_space(3))) void*)l, 16, 0, 0);
}

// bijective XCD-chunk swizzle (m204): each XCD gets a contiguous grid chunk.
__device__ __forceinline__ int xcd_swizzle(int orig, int nwg) {
  int q = nwg >> 3, r = nwg & 7;
  int xcd = orig & 7, idx = orig >> 3;
  int base = (xcd < r) ? xcd * (q + 1) : r * (q + 1) + (xcd - r) * q;
  return base + idx;
}

// ---------------- w1/w3 -> interleaved fp16 slice  [E][2*FS][D] -------------
__global__ __launch_bounds__(256) void cvt_w13_kernel(const float* __restrict__ w1,
                                                      const float* __restrict__ w3,
                                                      f16* __restrict__ w13,
                                                      int D, int F, int FS, int fbase) {
  long i = (long)blockIdx.x * 256 + threadIdx.x;          // float4 id
  long n4 = (long)NEXP * 2 * FS * (D / 4);
  if (i >= n4) return;
  int d4 = (int)(i % (D / 4));
  int rr = (int)((i / (D / 4)) % (2 * FS));
  int e  = (int)(i / ((long)(D / 4) * 2 * FS));
  const float* src = ((rr & 1) ? w3 : w1) + ((long)e * F + fbase + (rr >> 1)) * D + d4 * 4;
  float4 v = *(const float4*)src;
  f16x4 o = {(f16)v.x, (f16)v.y, (f16)v.z, (f16)v.w};
  *(f16x4*)(w13 + i * 4) = o;
}

// ---------------- w2 -> fp16 k-slice  [E][D][FS] ---------------------------
__global__ __launch_bounds__(256) void cvt_w2_kernel(const float* __restrict__ w2,
                                                     f16* __restrict__ w2s,
                                                     int D, int F, int FS, int fbase) {
  long i = (long)blockIdx.x * 256 + threadIdx.x;          // float4 id
  long n4 = (long)NEXP * D * (FS / 4);
  if (i >= n4) return;
  int k4 = (int)(i % (FS / 4));
  int d  = (int)((i / (FS / 4)) % D);
  int e  = (int)(i / ((long)(FS / 4) * D));
  const float* src = w2 + ((long)e * D + d) * F + fbase + k4 * 4;
  float4 v = *(const float4*)src;
  f16x4 o = {(f16)v.x, (f16)v.y, (f16)v.z, (f16)v.w};
  *(f16x4*)(w2s + i * 4) = o;
}

// ---------------- gating: fp32 logits, top-2, x->fp16 (no atomics) ---------
__global__ __launch_bounds__(256) void gate_kernel(const float* __restrict__ x,
                                                   const float* __restrict__ gw,
                                                   f16* __restrict__ xb,
                                                   int* __restrict__ topk_id,
                                                   float* __restrict__ topk_w,
                                                   int D) {
  const int lane = threadIdx.x & 63;
  const int wave = threadIdx.x >> 6;
  const long tok = (long)blockIdx.x * 4 + wave;
  const float* xrow = x + tok * D;

  float part[NEXP];
#pragma unroll
  for (int e = 0; e < NEXP; ++e) part[e] = 0.f;

  for (int c = 0; c < D / 256; ++c) {
    int idx = (c * 64 + lane) * 4;
    float4 xv = *(const float4*)(xrow + idx);
    f16x4 o = {(f16)xv.x, (f16)xv.y, (f16)xv.z, (f16)xv.w};
    *(f16x4*)(xb + tok * D + idx) = o;
#pragma unroll
    for (int e = 0; e < NEXP; ++e) {
      float4 gv = *(const float4*)(gw + (long)e * D + idx);
      part[e] += xv.x * gv.x + xv.y * gv.y + xv.z * gv.z + xv.w * gv.w;
    }
  }
#pragma unroll
  for (int e = 0; e < NEXP; ++e)
    for (int off = 32; off; off >>= 1) part[e] += __shfl_xor(part[e], off);

  // top-2, lowest index wins ties (matches lax.top_k stable ordering)
  int i0 = 0; float m0 = part[0];
#pragma unroll
  for (int e = 1; e < NEXP; ++e) if (part[e] > m0) { m0 = part[e]; i0 = e; }
  int i1 = (i0 == 0) ? 1 : 0; float m1 = part[i1];
#pragma unroll
  for (int e = 0; e < NEXP; ++e)
    if (e != i0 && e != ((i0 == 0) ? 1 : 0) && part[e] > m1) { m1 = part[e]; i1 = e; }

  if (lane == 0) {
    // renormalized top-2 softmax == sigmoid of logit difference (fp32 exact)
    float w0 = 1.f / (1.f + expf(m1 - m0));
    float w1 = 1.f / (1.f + expf(m0 - m1));
    topk_id[2 * tok] = i0; topk_id[2 * tok + 1] = i1;
    topk_w[2 * tok] = w0;  topk_w[2 * tok + 1] = w1;
  }
}

// ---------------- per-block expert histogram (LDS, no global contention) ----
__global__ __launch_bounds__(256) void count_kernel(const int* __restrict__ topk_id,
                                                    int* __restrict__ meta, int n2) {
  __shared__ int h[NEXP];
  const int t = threadIdx.x;
  if (t < NEXP) h[t] = 0;
  __syncthreads();
  const int lo = blockIdx.x * CHUNK;
  const int hi = min(n2, lo + CHUNK);
  for (int i = lo + t; i < hi; i += 256) atomicAdd(&h[topk_id[i]], 1);
  __syncthreads();
  if (t < NEXP) meta[M_PART + blockIdx.x * NEXP + t] = h[t];
}

// ---------------- offsets + both tile maps + bases + pad fill --------------
__global__ void setup_kernel(int* __restrict__ meta, int* __restrict__ routed_token,
                             float* __restrict__ routed_w, int MT, int MT2, int CB) {
  __shared__ int s_off[NEXP], s_cnt[NEXP], s_tot;
  const int t = threadIdx.x;
  if (t == 0) {
    int cnt[NEXP];
    for (int e = 0; e < NEXP; ++e) cnt[e] = 0;
    for (int b = 0; b < CB; ++b)
      for (int e = 0; e < NEXP; ++e) cnt[e] += meta[M_PART + b * NEXP + e];
    int off = 0, tt = 0, t2 = 0;
    for (int e = 0; e < NEXP; ++e) {
      s_cnt[e] = cnt[e]; s_off[e] = off;
      meta[M_OFF + e] = off;
      int p = (cnt[e] + 127) & ~127;
      for (int i = 0; i < (p >> 7); ++i) {
        meta[M_TE + tt] = e; meta[M_TR + tt] = off + i * 128; ++tt;
      }
      int full = p >> 8;
      for (int i = 0; i < full; ++i) {
        meta[M_TE2 + t2] = e; meta[M_TR2 + t2] = off + i * 256; meta[M_RL2 + t2] = 256; ++t2;
      }
      if (p & 255) {  // odd number of 128-tiles -> straddle tile, 128 valid rows
        meta[M_TE2 + t2] = e; meta[M_TR2 + t2] = off + full * 256; meta[M_RL2 + t2] = 128; ++t2;
      }
      off += p;
    }
    meta[M_OFF + NEXP] = off; s_tot = off;
    for (; tt < MT; ++tt) meta[M_TE + tt] = -1;
    for (; t2 < MT2; ++t2) meta[M_TE2 + t2] = -1;
    // exclusive per-block scatter bases
    for (int e = 0; e < NEXP; ++e) {
      int run = meta[M_OFF + e];
      for (int b = 0; b < CB; ++b) {
        meta[M_BB + b * NEXP + e] = run;
        run += meta[M_PART + b * NEXP + e];
      }
    }
  }
  __syncthreads();
  for (int e = 0; e < NEXP; ++e) {
    int start = s_off[e] + s_cnt[e];
    int end = s_off[e] + ((s_cnt[e] + 127) & ~127);
    for (int i = start + t; i < end; i += blockDim.x) {
      routed_token[i] = 0;      // pad rows -> token 0 (finite garbage)
      routed_w[i] = 0.f;        // zero gate weight kills pad contribution
    }
  }
  // tail slack for straddle-tile over-reads (rows [tot, tot+256))
  for (int i = s_tot + t; i < s_tot + 256; i += blockDim.x) {
    routed_token[i] = 0; routed_w[i] = 0.f;
  }
}

// ---------------- scatter tokens into per-expert slots (LDS cursors) -------
__global__ __launch_bounds__(256) void scatter_kernel(const int* __restrict__ topk_id,
                                                      const float* __restrict__ topk_w,
                                                      const int* __restrict__ meta,
                                                      int* __restrict__ routed_token,
                                                      float* __restrict__ routed_w,
                                                      int* __restrict__ slot_pos,
                                                      int n2) {
  __shared__ int cur[NEXP];
  const int t = threadIdx.x;
  if (t < NEXP) cur[t] = meta[M_BB + blockIdx.x * NEXP + t];
  __syncthreads();
  const int lo = blockIdx.x * CHUNK;
  const int hi = min(n2, lo + CHUNK);
  for (int i = lo + t; i < hi; i += 256) {
    int e = topk_id[i];
    int pos = atomicAdd(&cur[e], 1);
    routed_token[pos] = i >> 1;
    routed_w[pos] = topk_w[i];
    slot_pos[i] = pos;
  }
}

// ---------------- GEMM1: 256x256 8-wave deep-pipelined -------------------
// Tile: 256 token-rows x 256 interleaved weight-rows (2j=w1, 2j+1=w3).
// 8 waves 2M x 4N (per-wave 128x64). BK=64, dbuf LDS (128 KiB), 4 phases
// per K-tile. Counted vmcnt(4) once per K-tile in steady state; vmcnt(0)
// at k==NT-2 (B-prefetch skipped there, so vmcnt(4) would leave the
// A(NT-1) stages in flight while iteration NT-1 reads them).
#define STAGE_A(kk, h) do { int cc = (kk) & 1;                                  \
    f16* d_ = smem + cc * 16384 + ((h) * 1024 + (t & ~63)) * 8;                 \
    gload_lds16(aSrc[h][0] + (long)(kk) * 64, d_);                              \
    gload_lds16(aSrc[h][1] + (long)(kk) * 64, d_ + 4096); } while (0)
#define STAGE_B(kk, h) do { int cc = (kk) & 1;                                  \
    f16* d_ = smem + 32768 + cc * 16384 + ((h) * 1024 + (t & ~63)) * 8;         \
    gload_lds16(bSrc[h][0] + (long)(kk) * 64, d_);                              \
    gload_lds16(bSrc[h][1] + (long)(kk) * 64, d_ + 4096); } while (0)
#define READ_A(MH) do {                                                         \
    _Pragma("unroll")                                                           \
    for (int mf = 0; mf < 4; ++mf) {                                            \
      _Pragma("unroll")                                                         \
      for (int ks = 0; ks < 2; ++ks) {                                          \
        int row = wr * 128 + (MH) * 64 + mf * 16 + rA;                          \
        int kg = ks * 4 + kgb;                                                  \
        aF[mf][ks] = *(const f16x8*)(Ab + row * 64 + ((kg ^ (row & 7)) * 8));   \
      } } } while (0)
#define READ_B(NH) do {                                                         \
    _Pragma("unroll")                                                           \
    for (int nf = 0; nf < 2; ++nf) {                                            \
      _Pragma("unroll")                                                         \
      for (int ks = 0; ks < 2; ++ks) {                                          \
        int row = wc * 64 + ((NH) * 2 + nf) * 16 + rA;                          \
        int kg = ks * 4 + kgb;                                                  \
        bF[(NH) * 2 + nf][ks] = *(const f16x8*)(Bb + row * 64 + ((kg ^ (row & 7)) * 8)); \
      } } } while (0)
#define MFMA_Q(MH, NH) do {                                                     \
    _Pragma("unroll")                                                           \
    for (int mf = 0; mf < 4; ++mf) {                                            \
      _Pragma("unroll")                                                         \
      for (int nf = 0; nf < 2; ++nf) {                                          \
        _Pragma("unroll")                                                       \
        for (int ks = 0; ks < 2; ++ks) {                                        \
          acc[(MH) * 4 + mf][(NH) * 2 + nf] = __builtin_amdgcn_mfma_f32_16x16x32_f16( \
              aF[mf][ks], bF[(NH) * 2 + nf][ks], acc[(MH) * 4 + mf][(NH) * 2 + nf], 0, 0, 0); \
        } } } } while (0)
#define PH_MID() do { __builtin_amdgcn_s_barrier();                             \
    __builtin_amdgcn_s_setprio(1); } while (0)
#define PH_END() do { __builtin_amdgcn_s_setprio(0);                            \
    __builtin_amdgcn_s_barrier(); } while (0)

__global__ __launch_bounds__(512, 2) void ffn1_kernel(const f16* __restrict__ xb,
                                                      const f16* __restrict__ w13,
                                                      const int* __restrict__ routed_token,
                                                      const float* __restrict__ routed_w,
                                                      const int* __restrict__ meta,
                                                      f16* __restrict__ hbuf,
                                                      int D, int FS) {
  const int NX = FS >> 7;                       // f-slices of 128
  const int wg = xcd_swizzle(blockIdx.x, gridDim.x);
  const int bx = wg % NX;
  const int by = wg / NX;
  const int e = meta[M_TE2 + by];
  if (e < 0) return;
  const int r0   = meta[M_TR2 + by];
  const int rlim = meta[M_RL2 + by];
  const int f0 = bx * 128;                      // f-cols per block

  __shared__ __align__(16) f16 smem[4 * 256 * 64];   // 128 KiB: A0|A1|B0|B1
  __shared__ float s_w[256];

  const int t = threadIdx.x;
  const int lane = t & 63;
  const int wave = t >> 6;        // 0..7
  const int wr = wave >> 2;       // 0..1 (M)
  const int wc = wave & 3;        // 0..3 (N)
  const int rA = lane & 15;
  const int kgb = lane >> 4;

  if (t < 256) s_w[t] = routed_w[r0 + t];

  // staging sources: half h in {0,1}, granule-call q in {0,1}
  // granule gi = q*512 + t -> row r = h*128 + (gi>>3), col-gran (gi&7)^(r&7)
  const f16* aSrc[2][2];
  const f16* bSrc[2][2];
#pragma unroll
  for (int h = 0; h < 2; ++h)
#pragma unroll
    for (int q = 0; q < 2; ++q) {
      int gi = q * 512 + t;
      int r = h * 128 + (gi >> 3);
      int sg = (gi & 7) ^ (r & 7);
      int tok = routed_token[r0 + r];
      aSrc[h][q] = xb + (long)tok * D + sg * 8;
      bSrc[h][q] = w13 + ((long)e * 2 * FS + 2 * f0 + r) * D + sg * 8;
    }

  fx4 acc[8][4];
#pragma unroll
  for (int i = 0; i < 8; ++i)
#pragma unroll
    for (int j = 0; j < 4; ++j) acc[i][j] = (fx4){0.f, 0.f, 0.f, 0.f};

  const int NT = D >> 6;          // K-tiles (>=2)

  // prologue: B(0), A(0), B(1) in flight; gate so B(0),A(0) landed
  STAGE_B(0, 0); STAGE_B(0, 1);
  STAGE_A(0, 0); STAGE_A(0, 1);
  STAGE_B(1, 0); STAGE_B(1, 1);
  asm volatile("s_waitcnt vmcnt(4)" ::: "memory");
  __builtin_amdgcn_s_barrier();

  for (int k = 0; k < NT; ++k) {
    const int c = k & 1;
    const f16* Ab = smem + c * 16384;
    const f16* Bb = smem + 32768 + c * 16384;
    f16x8 aF[4][2], bF[4][2];
    // ---- p1
    READ_A(0); READ_B(0);
    if (k + 1 < NT) STAGE_A(k + 1, 0);
    PH_MID(); MFMA_Q(0, 0); PH_END();
    // ---- p2
    READ_B(1);
    if (k + 1 < NT) STAGE_A(k + 1, 1);
    PH_MID(); MFMA_Q(0, 1); PH_END();
    // ---- p3
    READ_A(1);
    if (k + 2 < NT) STAGE_B(k + 2, 0);
    PH_MID(); MFMA_Q(1, 1); PH_END();
    // ---- p4 (register-only MFMA; K-tile gate, counted — never 0 in steady state)
    if (k + 2 < NT) STAGE_B(k + 2, 1);
    __builtin_amdgcn_s_setprio(1);
    MFMA_Q(1, 0);
    __builtin_amdgcn_s_setprio(0);
    if (k == NT - 2) asm volatile("s_waitcnt vmcnt(0)" ::: "memory");  // tail: A(NT-1) must land
    else             asm volatile("s_waitcnt vmcnt(4)" ::: "memory");
    __builtin_amdgcn_s_barrier();
  }

  // epilogue: dedup even(w1)/odd(w3) silu, scale by gate w, LDS transpose.
  f16* sH = smem;                       // [256][136] = 69.6 KB
  const int odd = lane & 1;
  const int j = (lane & 15) >> 1;
#pragma unroll
  for (int mf = 0; mf < 8; ++mf)
#pragma unroll
    for (int nfp = 0; nfp < 4; nfp += 2)
#pragma unroll
      for (int rg = 0; rg < 4; ++rg) {
        float v0 = acc[mf][nfp][rg];
        float v1 = acc[mf][nfp + 1][rg];
        float t0 = __shfl_xor(v0, 1);
        float t1 = __shfl_xor(v1, 1);
        float c1 = odd ? t1 : v0;
        float c3 = odd ? v1 : t0;
        float ex = __expf(-c1);
        float hv = c1 * c3 * __builtin_amdgcn_rcpf(1.f + ex);
        int ml = wr * 128 + mf * 16 + (lane >> 4) * 4 + rg;
        int fl = wc * 32 + (nfp + odd) * 8 + j;
        sH[ml * 136 + fl] = (f16)(hv * s_w[ml]);
      }
  __syncthreads();
#pragma unroll
  for (int qq = 0; qq < 8; ++qq) {
    int gi = qq * 512 + t;              // 4096 granules = 256 rows x 16
    int r = gi >> 4, gc = gi & 15;
    if (r < rlim)
      *(f16x8*)(hbuf + (long)(r0 + r) * FS + f0 + gc * 8) =
          *(const f16x8*)(sH + r * 136 + gc * 8);
  }
}

// ---------------- GEMM2: y[slot] = (h @ w2^T) slice (h pre-weighted) -------
// Linearized grid + XCD-chunk swizzle; x-fastest = d-slice for hbuf reuse.
__global__ __launch_bounds__(256) void ffn2_kernel(const f16* __restrict__ hbuf,
                                                   const f16* __restrict__ w2s,
                                                   const int* __restrict__ routed_token,
                                                   const int* __restrict__ meta,
                                                   float* __restrict__ out,
                                                   f16* __restrict__ ybuf,
                                                   int D, int FS) {
  const int NX = D >> 7;
  const int wg = xcd_swizzle(blockIdx.x, gridDim.x);
  const int bxx = wg % NX;
  const int by = wg / NX;
  const int e = meta[M_TE + by];
  if (e < 0) return;
  const int r0 = meta[M_TR + by];
  const int d0 = bxx * 128;

  __shared__ __align__(16) f16 smem[128 * 136];
  __shared__ int s_tok[128];
  f16* sA = smem;
  f16* sB = smem + 128 * 64;

  const int t = threadIdx.x;
  const int lane = t & 63;
  const int wave = t >> 6;
  const int wm = (wave & 1) * 64;
  const int wn = (wave >> 1) * 64;

  if (!ybuf && t < 128) s_tok[t] = routed_token[r0 + t];

  const int rb = t >> 3;
  const int sgg = (t & 7) ^ (rb & 7);
  const f16* aptr[4];
  const f16* bptr[4];
#pragma unroll
  for (int q = 0; q < 4; ++q) {
    int r = q * 32 + rb;
    aptr[q] = hbuf + (long)(r0 + r) * FS + sgg * 8;
    bptr[q] = w2s + ((long)e * D + d0 + r) * FS + sgg * 8;
  }
  f16* ldsA[4]; f16* ldsB[4];
#pragma unroll
  for (int q = 0; q < 4; ++q) {
    int gbase = (q * 256 + (t & ~63)) * 8;
    ldsA[q] = sA + gbase;
    ldsB[q] = sB + gbase;
  }

  fx4 acc[4][4];
#pragma unroll
  for (int i = 0; i < 4; ++i)
#pragma unroll
    for (int j = 0; j < 4; ++j) acc[i][j] = (fx4){0.f, 0.f, 0.f, 0.f};

  for (int kc = 0; kc < FS; kc += 64) {
#pragma unroll
    for (int q = 0; q < 4; ++q) {
      gload_lds16(aptr[q] + kc, ldsA[q]);
      gload_lds16(bptr[q] + kc, ldsB[q]);
    }
    __syncthreads();
#pragma unroll
    for (int ks = 0; ks < 2; ++ks) {
      f16x8 aF[4], bF[4];
      const int kg = ks * 4 + (lane >> 4);
#pragma unroll
      for (int mf = 0; mf < 4; ++mf) {
        int row = wm + mf * 16 + (lane & 15);
        aF[mf] = *(const f16x8*)(sA + row * 64 + (kg ^ (row & 7)) * 8);
      }
#pragma unroll
      for (int nf = 0; nf < 4; ++nf) {
        int row = wn + nf * 16 + (lane & 15);
        bF[nf] = *(const f16x8*)(sB + row * 64 + (kg ^ (row & 7)) * 8);
      }
#pragma unroll
      for (int mf = 0; mf < 4; ++mf)
#pragma unroll
        for (int nf = 0; nf < 4; ++nf)
          acc[mf][nf] = __builtin_amdgcn_mfma_f32_16x16x32_f16(aF[mf], bF[nf], acc[mf][nf], 0, 0, 0);
    }
    __syncthreads();
  }

  if (ybuf) {
    f16* sH = smem;                     // [128][136]
#pragma unroll
    for (int mf = 0; mf < 4; ++mf)
#pragma unroll
      for (int nf = 0; nf < 4; ++nf)
#pragma unroll
        for (int rg = 0; rg < 4; ++rg) {
          int row = wm + mf * 16 + (lane >> 4) * 4 + rg;
          int col = wn + nf * 16 + (lane & 15);
          sH[row * 136 + col] = (f16)acc[mf][nf][rg];
        }
    __syncthreads();
#pragma unroll
    for (int q = 0; q < 8; ++q) {
      int gi = q * 256 + t;
      int r = gi >> 4, c = (gi & 15) * 8;
      *(f16x8*)(ybuf + (long)(r0 + r) * D + d0 + c) = *(const f16x8*)(sH + r * 136 + c);
    }
  } else {
#pragma unroll
    for (int mf = 0; mf < 4; ++mf) {
#pragma unroll
      for (int rg = 0; rg < 4; ++rg) {
        int row = wm + mf * 16 + (lane >> 4) * 4 + rg;
        long obase = (long)s_tok[row] * D + d0;
#pragma unroll
        for (int nf = 0; nf < 4; ++nf) {
          int nl = wn + nf * 16 + (lane & 15);
          atomicAdd(out + obase + nl, acc[mf][nf][rg]);
        }
      }
    }
  }
}

// ---------------- combine: out[tok] = y[slot0] + y[slot1] ------------------
__global__ __launch_bounds__(256) void combine_kernel(const f16* __restrict__ y,
                                                      const int* __restrict__ slot_pos,
                                                      float* __restrict__ out, int D) {
  const long tok = blockIdx.x;
  const int g = threadIdx.x * 8;
  const int p0 = slot_pos[2 * tok];
  const int p1 = slot_pos[2 * tok + 1];
  f16x8 a = *(const f16x8*)(y + (long)p0 * D + g);
  f16x8 b = *(const f16x8*)(y + (long)p1 * D + g);
  float* op = out + tok * D + g;
  float4 o0 = {(float)a[0] + (float)b[0], (float)a[1] + (float)b[1],
               (float)a[2] + (float)b[2], (float)a[3] + (float)b[3]};
  float4 o1 = {(float)a[4] + (float)b[4], (float)a[5] + (float)b[5],
               (float)a[6] + (float)b[6], (float)a[7] + (float)b[7]};
  *(float4*)op = o0;
  *(float4*)(op + 4) = o1;
}

// ---------------------------------------------------------------------------
extern "C" void kernel_launch(void* const* d_in, const int* in_sizes, int n_in,
                              void* d_out, int out_size, void* d_ws, size_t ws_size,
                              hipStream_t stream) {
  const float* x  = (const float*)d_in[0];
  const float* gw = (const float*)d_in[1];
  const float* w1 = (const float*)d_in[2];
  const float* w2 = (const float*)d_in[3];
  const float* w3 = (const float*)d_in[4];
  float* out = (float*)d_out;

  const int E = NEXP;
  const int D = in_sizes[1] / E;                              // 1024
  const long N = (long)in_sizes[0] / D;                       // 16384
  const int F = (int)((long)in_sizes[2] / ((long)E * D));     // 2048
  const int MT = (int)(2 * N / 128 + E);                      // 264 128-tiles max
  const int MT2 = (int)(2 * N / 256 + E);                     // 136 256-tiles max
  const long RMAX = (long)MT * 128;
  const long out_bytes = (long)out_size * 4;
  const int n2 = (int)(2 * N);
  const int CB = (n2 + CHUNK - 1) / CHUNK;                    // 32 routing blocks

  char* base = (char*)d_ws;
  long off = 0;
  int*   meta         = (int*)(base + off); off += 8 * 1024;
  int*   topk_id      = (int*)(base + off); off += 2 * N * 4;
  float* topk_w       = (float*)(base + off); off += 2 * N * 4;
  int*   slot_pos     = (int*)(base + off); off += 2 * N * 4;
  int*   routed_token = (int*)(base + off); off += (RMAX + 256) * 4;
  float* routed_w     = (float*)(base + off); off += (RMAX + 256) * 4;
  off = (off + 255) & ~255L;
  const long small_end = off;

  const long w13_b = (long)E * 2 * F * D * 2;
  const long xb_b  = N * (long)D * 2;

  int S = 0; bool w13_in_dout = false; bool use_y = false;
  f16 *xb = nullptr, *w2s = nullptr, *hbuf = nullptr, *ybuf = nullptr, *w13 = nullptr;
  int FS = F;

  if (out_bytes >= w13_b) {
    const long w2s_b  = (long)E * D * F * 2;
    const long hbuf_b = RMAX * (long)F * 2;
    const long ybuf_b = RMAX * (long)D * 2;
    const long ovl_b  = (xb_b > ybuf_b) ? xb_b : ybuf_b;
    // Layout A: [small | w2s | hbuf | xb==ybuf overlay]  (xb dead after ffn1)
    if (small_end + w2s_b + hbuf_b + ovl_b <= (long)ws_size) {
      S = 1; w13_in_dout = true; use_y = true;
      long o = small_end;
      w2s  = (f16*)(base + o); o += w2s_b;
      hbuf = (f16*)(base + o); o += hbuf_b;
      xb   = (f16*)(base + o);
      ybuf = xb;                       // alias: ffn2 writes after ffn1's last xb read
      w13  = (f16*)d_out;
    } else if (small_end + xb_b + w2s_b + hbuf_b <= (long)ws_size) {
      S = 1; w13_in_dout = true;
      long o = small_end;
      xb   = (f16*)(base + o); o += xb_b;
      w2s  = (f16*)(base + o); o += w2s_b;
      hbuf = (f16*)(base + o);
      w13  = (f16*)d_out;
    }
  }
  if (!S) {
    const int cands[4] = {2, 4, 8, 16};
    for (int ci = 0; ci < 4 && !S; ++ci) {
      int s = cands[ci];
      if (F % (128 * s)) continue;
      long FSl = F / s;
      long w2s_b  = (long)E * D * FSl * 2;
      long hbuf_b = RMAX * FSl * 2;
      long w13s_b = (long)E * 2 * FSl * D * 2;
      if (small_end + xb_b + w2s_b + hbuf_b + w13s_b <= (long)ws_size) {
        S = s; FS = (int)FSl;
        long o = small_end;
        xb   = (f16*)(base + o); o += xb_b;
        w2s  = (f16*)(base + o); o += w2s_b;
        hbuf = (f16*)(base + o); o += hbuf_b;
        w13  = (f16*)(base + o);
      }
    }
  }
  if (!S) return;

  hipMemsetAsync(meta, 0, 8 * 1024, stream);
  gate_kernel<<<(int)(N / 4), 256, 0, stream>>>(x, gw, xb, topk_id, topk_w, D);
  count_kernel<<<CB, 256, 0, stream>>>(topk_id, meta, n2);
  setup_kernel<<<1, 256, 0, stream>>>(meta, routed_token, routed_w, MT, MT2, CB);
  scatter_kernel<<<CB, 256, 0, stream>>>(topk_id, topk_w, meta, routed_token, routed_w,
                                         slot_pos, n2);

  const long n13 = (long)E * 2 * FS * (D / 4);
  const long nw2 = (long)E * D * (FS / 4);
  const int b13 = (int)((n13 + 255) / 256);
  const int bw2 = (int)((nw2 + 255) / 256);

  const int nwg1 = (FS / 128) * MT2;
  const int nwg2 = (D / 128) * MT;

  if (w13_in_dout) {
    cvt_w13_kernel<<<b13, 256, 0, stream>>>(w1, w3, w13, D, F, FS, 0);
    cvt_w2_kernel<<<bw2, 256, 0, stream>>>(w2, w2s, D, F, FS, 0);
    ffn1_kernel<<<nwg1, 512, 0, stream>>>(xb, w13, routed_token, routed_w, meta, hbuf, D, FS);
    if (use_y) {
      ffn2_kernel<<<nwg2, 256, 0, stream>>>(hbuf, w2s, routed_token, meta, out, ybuf, D, FS);
      combine_kernel<<<(int)N, D / 8, 0, stream>>>(ybuf, slot_pos, out, D);
    } else {
      hipMemsetAsync(out, 0, out_bytes, stream);
      ffn2_kernel<<<nwg2, 256, 0, stream>>>(hbuf, w2s, routed_token, meta, out, nullptr, D, FS);
    }
  } else {
    hipMemsetAsync(out, 0, out_bytes, stream);
    for (int s = 0; s < S; ++s) {
      int fbase = s * FS;
      cvt_w13_kernel<<<b13, 256, 0, stream>>>(w1, w3, w13, D, F, FS, fbase);
      cvt_w2_kernel<<<bw2, 256, 0, stream>>>(w2, w2s, D, F, FS, fbase);
      ffn1_kernel<<<nwg1, 512, 0, stream>>>(xb, w13, routed_token, routed_w, meta, hbuf, D, FS);
      ffn2_kernel<<<nwg2, 256, 0, stream>>>(hbuf, w2s, routed_token, meta, out, nullptr, D, FS);
    }
  }
}

// Round 7
// 859.495 us; speedup vs baseline: 1.1012x; 1.0812x over previous
//
#include <hip/hip_runtime.h>
#include <stdint.h>

// ---------------------------------------------------------------------------
// MoE top-2 FFN on gfx950: fp32 gating (exact expert selection), fp16 MFMA
// grouped GEMMs, routed ybuf + gather combine.
// R9->R10: 2-blocks/CU pipelined GEMMs. 256^2 pipeline was stuck at 1
// block/CU (128KiB LDS + 244 regs) -> 45% stall. New geometry: 128x256
// tile, BK=32, 8 waves of 64x64 (acc 64 f32, ~121 regs, LDS 49KB dbuf) ->
// 2 blocks/CU co-residency + counted vmcnt(2) pipeline + setprio. Mod-4
// LDS swizzle g^((r^(r>>2))&3) keeps bank conflicts at free 2-way.
// ffn2 ported to the same structure (128 rows x 256 d-cols). Both GEMMs
// use the plain 128-row tile map (no straddle).
// ---------------------------------------------------------------------------

typedef _Float16 f16;
typedef f16  f16x8 __attribute__((ext_vector_type(8)));
typedef f16  f16x4 __attribute__((ext_vector_type(4)));
typedef float fx4  __attribute__((ext_vector_type(4)));

#define NEXP 8
#define CHUNK 1024          // assignments per routing block
// meta layout (ints):
#define M_PART 0            // [32*8] per-block expert counts
#define M_OFF  256          // [9] expert slot offsets (padded 128)
#define M_BB   272          // [32*8] per-block scatter bases
#define M_TE   528          // [<=512] 128-tile -> expert
#define M_TR   1040         // [<=512] 128-tile -> first slot row

__device__ __forceinline__ void gload_lds16(const f16* g, f16* l) {
  // global->LDS DMA, 16 B/lane. LDS dest is wave-uniform base + lane*16.
  __builtin_amdgcn_global_load_lds(
      (const __attribute__((address_space(1))) void*)g,
      (__attribute__((address_space(3))) void*)l, 16, 0, 0);
}

// bijective XCD-chunk swizzle (m204): each XCD gets a contiguous grid chunk.
__device__ __forceinline__ int xcd_swizzle(int orig, int nwg) {
  int q = nwg >> 3, r = nwg & 7;
  int xcd = orig & 7, idx = orig >> 3;
  int base = (xcd < r) ? xcd * (q + 1) : r * (q + 1) + (xcd - r) * q;
  return base + idx;
}

// mod-4 granule swizzle for BK=32 rows (stride 64B). Plain g^(r&3) leaves a
// 4-way conflict (lanes i,i+4 alias); folding bit r>>2 makes it 2-way (free).
__device__ __forceinline__ int swz4(int g, int r) {
  return g ^ ((r ^ (r >> 2)) & 3);
}

// ---------------- w1/w3 -> interleaved fp16 slice  [E][2*FS][D] -------------
__global__ __launch_bounds__(256) void cvt_w13_kernel(const float* __restrict__ w1,
                                                      const float* __restrict__ w3,
                                                      f16* __restrict__ w13,
                                                      int D, int F, int FS, int fbase) {
  long i = (long)blockIdx.x * 256 + threadIdx.x;          // float4 id
  long n4 = (long)NEXP * 2 * FS * (D / 4);
  if (i >= n4) return;
  int d4 = (int)(i % (D / 4));
  int rr = (int)((i / (D / 4)) % (2 * FS));
  int e  = (int)(i / ((long)(D / 4) * 2 * FS));
  const float* src = ((rr & 1) ? w3 : w1) + ((long)e * F + fbase + (rr >> 1)) * D + d4 * 4;
  float4 v = *(const float4*)src;
  f16x4 o = {(f16)v.x, (f16)v.y, (f16)v.z, (f16)v.w};
  *(f16x4*)(w13 + i * 4) = o;
}

// ---------------- w2 -> fp16 k-slice  [E][D][FS] ---------------------------
__global__ __launch_bounds__(256) void cvt_w2_kernel(const float* __restrict__ w2,
                                                     f16* __restrict__ w2s,
                                                     int D, int F, int FS, int fbase) {
  long i = (long)blockIdx.x * 256 + threadIdx.x;          // float4 id
  long n4 = (long)NEXP * D * (FS / 4);
  if (i >= n4) return;
  int k4 = (int)(i % (FS / 4));
  int d  = (int)((i / (FS / 4)) % D);
  int e  = (int)(i / ((long)(FS / 4) * D));
  const float* src = w2 + ((long)e * D + d) * F + fbase + k4 * 4;
  float4 v = *(const float4*)src;
  f16x4 o = {(f16)v.x, (f16)v.y, (f16)v.z, (f16)v.w};
  *(f16x4*)(w2s + i * 4) = o;
}

// ---------------- gating: fp32 logits, top-2, x->fp16 (no atomics) ---------
__global__ __launch_bounds__(256) void gate_kernel(const float* __restrict__ x,
                                                   const float* __restrict__ gw,
                                                   f16* __restrict__ xb,
                                                   int* __restrict__ topk_id,
                                                   float* __restrict__ topk_w,
                                                   int D) {
  const int lane = threadIdx.x & 63;
  const int wave = threadIdx.x >> 6;
  const long tok = (long)blockIdx.x * 4 + wave;
  const float* xrow = x + tok * D;

  float part[NEXP];
#pragma unroll
  for (int e = 0; e < NEXP; ++e) part[e] = 0.f;

  for (int c = 0; c < D / 256; ++c) {
    int idx = (c * 64 + lane) * 4;
    float4 xv = *(const float4*)(xrow + idx);
    f16x4 o = {(f16)xv.x, (f16)xv.y, (f16)xv.z, (f16)xv.w};
    *(f16x4*)(xb + tok * D + idx) = o;
#pragma unroll
    for (int e = 0; e < NEXP; ++e) {
      float4 gv = *(const float4*)(gw + (long)e * D + idx);
      part[e] += xv.x * gv.x + xv.y * gv.y + xv.z * gv.z + xv.w * gv.w;
    }
  }
#pragma unroll
  for (int e = 0; e < NEXP; ++e)
    for (int off = 32; off; off >>= 1) part[e] += __shfl_xor(part[e], off);

  // top-2, lowest index wins ties (matches lax.top_k stable ordering)
  int i0 = 0; float m0 = part[0];
#pragma unroll
  for (int e = 1; e < NEXP; ++e) if (part[e] > m0) { m0 = part[e]; i0 = e; }
  int i1 = (i0 == 0) ? 1 : 0; float m1 = part[i1];
#pragma unroll
  for (int e = 0; e < NEXP; ++e)
    if (e != i0 && e != ((i0 == 0) ? 1 : 0) && part[e] > m1) { m1 = part[e]; i1 = e; }

  if (lane == 0) {
    // renormalized top-2 softmax == sigmoid of logit difference (fp32 exact)
    float w0 = 1.f / (1.f + expf(m1 - m0));
    float w1 = 1.f / (1.f + expf(m0 - m1));
    topk_id[2 * tok] = i0; topk_id[2 * tok + 1] = i1;
    topk_w[2 * tok] = w0;  topk_w[2 * tok + 1] = w1;
  }
}

// ---------------- per-block expert histogram (LDS, no global contention) ----
__global__ __launch_bounds__(256) void count_kernel(const int* __restrict__ topk_id,
                                                    int* __restrict__ meta, int n2) {
  __shared__ int h[NEXP];
  const int t = threadIdx.x;
  if (t < NEXP) h[t] = 0;
  __syncthreads();
  const int lo = blockIdx.x * CHUNK;
  const int hi = min(n2, lo + CHUNK);
  for (int i = lo + t; i < hi; i += 256) atomicAdd(&h[topk_id[i]], 1);
  __syncthreads();
  if (t < NEXP) meta[M_PART + blockIdx.x * NEXP + t] = h[t];
}

// ---------------- offsets + tile map + bases + pad fill --------------------
__global__ void setup_kernel(int* __restrict__ meta, int* __restrict__ routed_token,
                             float* __restrict__ routed_w, int MT, int CB) {
  __shared__ int s_off[NEXP], s_cnt[NEXP], s_tot;
  const int t = threadIdx.x;
  if (t == 0) {
    int cnt[NEXP];
    for (int e = 0; e < NEXP; ++e) cnt[e] = 0;
    for (int b = 0; b < CB; ++b)
      for (int e = 0; e < NEXP; ++e) cnt[e] += meta[M_PART + b * NEXP + e];
    int off = 0, tt = 0;
    for (int e = 0; e < NEXP; ++e) {
      s_cnt[e] = cnt[e]; s_off[e] = off;
      meta[M_OFF + e] = off;
      int p = (cnt[e] + 127) & ~127;
      for (int i = 0; i < (p >> 7); ++i) {
        meta[M_TE + tt] = e; meta[M_TR + tt] = off + i * 128; ++tt;
      }
      off += p;
    }
    meta[M_OFF + NEXP] = off; s_tot = off;
    for (; tt < MT; ++tt) meta[M_TE + tt] = -1;
    // exclusive per-block scatter bases
    for (int e = 0; e < NEXP; ++e) {
      int run = meta[M_OFF + e];
      for (int b = 0; b < CB; ++b) {
        meta[M_BB + b * NEXP + e] = run;
        run += meta[M_PART + b * NEXP + e];
      }
    }
  }
  __syncthreads();
  for (int e = 0; e < NEXP; ++e) {
    int start = s_off[e] + s_cnt[e];
    int end = s_off[e] + ((s_cnt[e] + 127) & ~127);
    for (int i = start + t; i < end; i += blockDim.x) {
      routed_token[i] = 0;      // pad rows -> token 0 (finite garbage)
      routed_w[i] = 0.f;        // zero gate weight kills pad contribution
    }
  }
  // safety slack beyond the last tile
  for (int i = s_tot + t; i < s_tot + 256; i += blockDim.x) {
    routed_token[i] = 0; routed_w[i] = 0.f;
  }
}

// ---------------- scatter tokens into per-expert slots (LDS cursors) -------
__global__ __launch_bounds__(256) void scatter_kernel(const int* __restrict__ topk_id,
                                                      const float* __restrict__ topk_w,
                                                      const int* __restrict__ meta,
                                                      int* __restrict__ routed_token,
                                                      float* __restrict__ routed_w,
                                                      int* __restrict__ slot_pos,
                                                      int n2) {
  __shared__ int cur[NEXP];
  const int t = threadIdx.x;
  if (t < NEXP) cur[t] = meta[M_BB + blockIdx.x * NEXP + t];
  __syncthreads();
  const int lo = blockIdx.x * CHUNK;
  const int hi = min(n2, lo + CHUNK);
  for (int i = lo + t; i < hi; i += 256) {
    int e = topk_id[i];
    int pos = atomicAdd(&cur[e], 1);
    routed_token[pos] = i >> 1;
    routed_w[pos] = topk_w[i];
    slot_pos[i] = pos;
  }
}

// ============ shared pipelined-GEMM skeleton (128 x 256, BK=32) ============
// 8 waves 2M x 4N (64x64 each). A tile 128x32 (1 gload call), B tile 256x32
// (2 calls). Dbuf LDS 24576 f16. Per K-tile: reads(8) + stageA -> BAR ->
// MFMA(nf 0,1) -> lgkm(0) -> BAR -> stageB(k+2) -> MFMA(nf 2,3) -> vmcnt ->
// BAR. stageB overwrites the CURRENT B buffer: safe because every wave's B
// reads complete (lgkmcnt(0)) before the BAR that precedes stageB.
// vmcnt(2) leaves only B(k+2)'s 2 loads in flight; forces A(k+1)+B(k+1).

#define PIPE_LOOP(AB_READS, MFMA1, MFMA2)                                      \
  for (int k = 0; k < NT; ++k) {                                               \
    const f16* Ab = smem + (k & 1) * 4096;                                     \
    const f16* Bb = smem + 8192 + (k & 1) * 8192;                              \
    f16x8 aF[4], bF[4];                                                        \
    AB_READS;                                                                  \
    if (k + 1 < NT) STAGE_A(k + 1);                                            \
    __builtin_amdgcn_s_barrier();                                              \
    __builtin_amdgcn_s_setprio(1);                                             \
    MFMA1;                                                                     \
    __builtin_amdgcn_s_setprio(0);                                             \
    asm volatile("s_waitcnt lgkmcnt(0)" ::: "memory");                         \
    __builtin_amdgcn_s_barrier();                                              \
    if (k + 2 < NT) STAGE_B(k + 2);                                            \
    __builtin_amdgcn_s_setprio(1);                                             \
    MFMA2;                                                                     \
    __builtin_amdgcn_s_setprio(0);                                             \
    if (k >= NT - 2) asm volatile("s_waitcnt vmcnt(0)" ::: "memory");          \
    else             asm volatile("s_waitcnt vmcnt(2)" ::: "memory");          \
    __builtin_amdgcn_s_barrier();                                              \
  }

#define STAGE_A(kk) gload_lds16(aSrc + (long)(kk) * 32,                        \
                                smem + ((kk) & 1) * 4096 + (t & ~63) * 8)
#define STAGE_B(kk) do {                                                       \
    f16* d_ = smem + 8192 + ((kk) & 1) * 8192 + (t & ~63) * 8;                 \
    gload_lds16(bSrc0 + (long)(kk) * 32, d_);                                  \
    gload_lds16(bSrc1 + (long)(kk) * 32, d_ + 4096); } while (0)

#define READS_AB do {                                                          \
    _Pragma("unroll")                                                          \
    for (int nf = 0; nf < 4; ++nf) {                                           \
      int row = wc * 64 + nf * 16 + rA;                                        \
      bF[nf] = *(const f16x8*)(Bb + row * 32 + swz4(kgb, row) * 8);            \
    }                                                                          \
    _Pragma("unroll")                                                          \
    for (int mf = 0; mf < 4; ++mf) {                                           \
      int row = wr * 64 + mf * 16 + rA;                                        \
      aF[mf] = *(const f16x8*)(Ab + row * 32 + swz4(kgb, row) * 8);            \
    } } while (0)

#define MFMA_H(NLO) do {                                                       \
    _Pragma("unroll")                                                          \
    for (int mf = 0; mf < 4; ++mf) {                                           \
      _Pragma("unroll")                                                        \
      for (int nf = (NLO); nf < (NLO) + 2; ++nf)                               \
        acc[mf][nf] = __builtin_amdgcn_mfma_f32_16x16x32_f16(                  \
            aF[mf], bF[nf], acc[mf][nf], 0, 0, 0);                             \
    } } while (0)

#define PIPE_PROLOGUE do {                                                     \
    STAGE_B(0); STAGE_A(0); STAGE_B(1);                                        \
    asm volatile("s_waitcnt vmcnt(2)" ::: "memory");                           \
    __builtin_amdgcn_s_barrier(); } while (0)

// ---------------- GEMM1: h = gate_w * silu(X w1^T) * (X w3^T) --------------
// Tile 128 token-rows x 256 interleaved weight-rows (= 128 f-cols).
__global__ __launch_bounds__(512, 4) void ffn1_kernel(const f16* __restrict__ xb,
                                                      const f16* __restrict__ w13,
                                                      const int* __restrict__ routed_token,
                                                      const float* __restrict__ routed_w,
                                                      const int* __restrict__ meta,
                                                      f16* __restrict__ hbuf,
                                                      int D, int FS) {
  const int NX = FS >> 7;
  const int wg = xcd_swizzle(blockIdx.x, gridDim.x);
  const int bx = wg % NX, by = wg / NX;
  const int e = meta[M_TE + by];
  if (e < 0) return;
  const int r0 = meta[M_TR + by];
  const int f0 = bx * 128;

  __shared__ __align__(16) f16 smem[24576];   // A dbuf 2x4096 | B dbuf 2x8192
  __shared__ float s_w[128];

  const int t = threadIdx.x;
  const int lane = t & 63;
  const int wave = t >> 6;
  const int wr = wave >> 2;       // 0..1 (M)
  const int wc = wave & 3;        // 0..3 (N)
  const int rA = lane & 15;
  const int kgb = lane >> 4;

  if (t < 128) s_w[t] = routed_w[r0 + t];

  // staging sources (per-lane global addrs carry the mod-4 swizzle)
  const f16* aSrc;
  const f16* bSrc0;
  const f16* bSrc1;
  {
    int r = t >> 2, sg = swz4(t & 3, r);
    aSrc = xb + (long)routed_token[r0 + r] * D + sg * 8;
    bSrc0 = w13 + ((long)e * 2 * FS + 2 * f0 + r) * D + sg * 8;
    int r1 = 128 + r;
    int sg1 = swz4(t & 3, r1);
    bSrc1 = w13 + ((long)e * 2 * FS + 2 * f0 + r1) * D + sg1 * 8;
  }

  fx4 acc[4][4];
#pragma unroll
  for (int i = 0; i < 4; ++i)
#pragma unroll
    for (int j = 0; j < 4; ++j) acc[i][j] = (fx4){0.f, 0.f, 0.f, 0.f};

  const int NT = D >> 5;
  PIPE_PROLOGUE;
  PIPE_LOOP(READS_AB, MFMA_H(0), MFMA_H(2));

  // epilogue: dedup even(w1)/odd(w3) silu, scale by gate w, LDS transpose.
  f16* sH = smem;                       // [128][136]
  const int wm = wr * 64, wn = wc * 64;
  const int odd = lane & 1;
  const int j = (lane & 15) >> 1;
#pragma unroll
  for (int mf = 0; mf < 4; ++mf)
#pragma unroll
    for (int nfp = 0; nfp < 4; nfp += 2)
#pragma unroll
      for (int rg = 0; rg < 4; ++rg) {
        float v0 = acc[mf][nfp][rg];
        float v1 = acc[mf][nfp + 1][rg];
        float t0 = __shfl_xor(v0, 1);
        float t1 = __shfl_xor(v1, 1);
        float c1 = odd ? t1 : v0;
        float c3 = odd ? v1 : t0;
        float ex = __expf(-c1);
        float hv = c1 * c3 * __builtin_amdgcn_rcpf(1.f + ex);
        int ml = wm + mf * 16 + (lane >> 4) * 4 + rg;
        int fl = (wn >> 1) + (nfp + odd) * 8 + j;
        sH[ml * 136 + fl] = (f16)(hv * s_w[ml]);
      }
  __syncthreads();
#pragma unroll
  for (int qq = 0; qq < 4; ++qq) {
    int gi = qq * 512 + t;              // 2048 granules = 128 rows x 16
    int r = gi >> 4, gc = gi & 15;
    *(f16x8*)(hbuf + (long)(r0 + r) * FS + f0 + gc * 8) =
        *(const f16x8*)(sH + r * 136 + gc * 8);
  }
}

// ---------------- GEMM2: y[slot] = (h @ w2^T) slice (h pre-weighted) -------
// Tile 128 slot-rows x 256 d-cols. Same pipeline skeleton, K = FS.
__global__ __launch_bounds__(512, 4) void ffn2_kernel(const f16* __restrict__ hbuf,
                                                      const f16* __restrict__ w2s,
                                                      const int* __restrict__ routed_token,
                                                      const int* __restrict__ meta,
                                                      float* __restrict__ out,
                                                      f16* __restrict__ ybuf,
                                                      int D, int FS) {
  const int NX = D >> 8;                        // d-slices of 256
  const int wg = xcd_swizzle(blockIdx.x, gridDim.x);
  const int bx = wg % NX, by = wg / NX;
  const int e = meta[M_TE + by];
  if (e < 0) return;
  const int r0 = meta[M_TR + by];
  const int d0 = bx * 256;

  __shared__ __align__(16) f16 smem[33792];     // staging 24576; sH [128][264]
  __shared__ int s_tok[128];

  const int t = threadIdx.x;
  const int lane = t & 63;
  const int wave = t >> 6;
  const int wr = wave >> 2;
  const int wc = wave & 3;
  const int rA = lane & 15;
  const int kgb = lane >> 4;

  if (!ybuf && t < 128) s_tok[t] = routed_token[r0 + t];

  const f16* aSrc;
  const f16* bSrc0;
  const f16* bSrc1;
  {
    int r = t >> 2, sg = swz4(t & 3, r);
    aSrc = hbuf + (long)(r0 + r) * FS + sg * 8;
    bSrc0 = w2s + ((long)e * D + d0 + r) * FS + sg * 8;
    int r1 = 128 + r;
    int sg1 = swz4(t & 3, r1);
    bSrc1 = w2s + ((long)e * D + d0 + r1) * FS + sg1 * 8;
  }

  fx4 acc[4][4];
#pragma unroll
  for (int i = 0; i < 4; ++i)
#pragma unroll
    for (int j = 0; j < 4; ++j) acc[i][j] = (fx4){0.f, 0.f, 0.f, 0.f};

  const int NT = FS >> 5;
  PIPE_PROLOGUE;
  PIPE_LOOP(READS_AB, MFMA_H(0), MFMA_H(2));

  if (ybuf) {
    f16* sH = smem;                     // [128][264]
#pragma unroll
    for (int mf = 0; mf < 4; ++mf)
#pragma unroll
      for (int nf = 0; nf < 4; ++nf)
#pragma unroll
        for (int rg = 0; rg < 4; ++rg) {
          int row = wr * 64 + mf * 16 + (lane >> 4) * 4 + rg;
          int col = wc * 64 + nf * 16 + (lane & 15);
          sH[row * 264 + col] = (f16)acc[mf][nf][rg];
        }
    __syncthreads();
#pragma unroll
    for (int qq = 0; qq < 8; ++qq) {
      int gi = qq * 512 + t;            // 4096 granules = 128 rows x 32
      int r = gi >> 5, gc = gi & 31;
      *(f16x8*)(ybuf + (long)(r0 + r) * D + d0 + gc * 8) =
          *(const f16x8*)(sH + r * 264 + gc * 8);
    }
  } else {
#pragma unroll
    for (int mf = 0; mf < 4; ++mf) {
#pragma unroll
      for (int rg = 0; rg < 4; ++rg) {
        int row = wr * 64 + mf * 16 + (lane >> 4) * 4 + rg;
        long obase = (long)s_tok[row] * D + d0;
#pragma unroll
        for (int nf = 0; nf < 4; ++nf) {
          int nl = wc * 64 + nf * 16 + (lane & 15);
          atomicAdd(out + obase + nl, acc[mf][nf][rg]);
        }
      }
    }
  }
}

// ---------------- combine: out[tok] = y[slot0] + y[slot1] ------------------
__global__ __launch_bounds__(256) void combine_kernel(const f16* __restrict__ y,
                                                      const int* __restrict__ slot_pos,
                                                      float* __restrict__ out, int D) {
  const long tok = blockIdx.x;
  const int g = threadIdx.x * 8;
  const int p0 = slot_pos[2 * tok];
  const int p1 = slot_pos[2 * tok + 1];
  f16x8 a = *(const f16x8*)(y + (long)p0 * D + g);
  f16x8 b = *(const f16x8*)(y + (long)p1 * D + g);
  float* op = out + tok * D + g;
  float4 o0 = {(float)a[0] + (float)b[0], (float)a[1] + (float)b[1],
               (float)a[2] + (float)b[2], (float)a[3] + (float)b[3]};
  float4 o1 = {(float)a[4] + (float)b[4], (float)a[5] + (float)b[5],
               (float)a[6] + (float)b[6], (float)a[7] + (float)b[7]};
  *(float4*)op = o0;
  *(float4*)(op + 4) = o1;
}

// ---------------------------------------------------------------------------
extern "C" void kernel_launch(void* const* d_in, const int* in_sizes, int n_in,
                              void* d_out, int out_size, void* d_ws, size_t ws_size,
                              hipStream_t stream) {
  const float* x  = (const float*)d_in[0];
  const float* gw = (const float*)d_in[1];
  const float* w1 = (const float*)d_in[2];
  const float* w2 = (const float*)d_in[3];
  const float* w3 = (const float*)d_in[4];
  float* out = (float*)d_out;

  const int E = NEXP;
  const int D = in_sizes[1] / E;                              // 1024
  const long N = (long)in_sizes[0] / D;                       // 16384
  const int F = (int)((long)in_sizes[2] / ((long)E * D));     // 2048
  const int MT = (int)(2 * N / 128 + E);                      // 264 128-tiles max
  const long RMAX = (long)MT * 128;
  const long out_bytes = (long)out_size * 4;
  const int n2 = (int)(2 * N);
  const int CB = (n2 + CHUNK - 1) / CHUNK;                    // 32 routing blocks

  char* base = (char*)d_ws;
  long off = 0;
  int*   meta         = (int*)(base + off); off += 8 * 1024;
  int*   topk_id      = (int*)(base + off); off += 2 * N * 4;
  float* topk_w       = (float*)(base + off); off += 2 * N * 4;
  int*   slot_pos     = (int*)(base + off); off += 2 * N * 4;
  int*   routed_token = (int*)(base + off); off += (RMAX + 256) * 4;
  float* routed_w     = (float*)(base + off); off += (RMAX + 256) * 4;
  off = (off + 255) & ~255L;
  const long small_end = off;

  const long w13_b = (long)E * 2 * F * D * 2;
  const long xb_b  = N * (long)D * 2;

  int S = 0; bool w13_in_dout = false; bool use_y = false;
  f16 *xb = nullptr, *w2s = nullptr, *hbuf = nullptr, *ybuf = nullptr, *w13 = nullptr;
  int FS = F;

  if (out_bytes >= w13_b) {
    const long w2s_b  = (long)E * D * F * 2;
    const long hbuf_b = RMAX * (long)F * 2;
    const long ybuf_b = RMAX * (long)D * 2;
    const long ovl_b  = (xb_b > ybuf_b) ? xb_b : ybuf_b;
    // Layout A: [small | w2s | hbuf | xb==ybuf overlay]  (xb dead after ffn1)
    if (small_end + w2s_b + hbuf_b + ovl_b <= (long)ws_size) {
      S = 1; w13_in_dout = true; use_y = true;
      long o = small_end;
      w2s  = (f16*)(base + o); o += w2s_b;
      hbuf = (f16*)(base + o); o += hbuf_b;
      xb   = (f16*)(base + o);
      ybuf = xb;                       // alias: ffn2 writes after ffn1's last xb read
      w13  = (f16*)d_out;
    } else if (small_end + xb_b + w2s_b + hbuf_b <= (long)ws_size) {
      S = 1; w13_in_dout = true;
      long o = small_end;
      xb   = (f16*)(base + o); o += xb_b;
      w2s  = (f16*)(base + o); o += w2s_b;
      hbuf = (f16*)(base + o);
      w13  = (f16*)d_out;
    }
  }
  if (!S) {
    const int cands[4] = {2, 4, 8, 16};
    for (int ci = 0; ci < 4 && !S; ++ci) {
      int s = cands[ci];
      if (F % (128 * s)) continue;
      long FSl = F / s;
      long w2s_b  = (long)E * D * FSl * 2;
      long hbuf_b = RMAX * FSl * 2;
      long w13s_b = (long)E * 2 * FSl * D * 2;
      if (small_end + xb_b + w2s_b + hbuf_b + w13s_b <= (long)ws_size) {
        S = s; FS = (int)FSl;
        long o = small_end;
        xb   = (f16*)(base + o); o += xb_b;
        w2s  = (f16*)(base + o); o += w2s_b;
        hbuf = (f16*)(base + o); o += hbuf_b;
        w13  = (f16*)(base + o);
      }
    }
  }
  if (!S) return;

  hipMemsetAsync(meta, 0, 8 * 1024, stream);
  gate_kernel<<<(int)(N / 4), 256, 0, stream>>>(x, gw, xb, topk_id, topk_w, D);
  count_kernel<<<CB, 256, 0, stream>>>(topk_id, meta, n2);
  setup_kernel<<<1, 256, 0, stream>>>(meta, routed_token, routed_w, MT, CB);
  scatter_kernel<<<CB, 256, 0, stream>>>(topk_id, topk_w, meta, routed_token, routed_w,
                                         slot_pos, n2);

  const long n13 = (long)E * 2 * FS * (D / 4);
  const long nw2 = (long)E * D * (FS / 4);
  const int b13 = (int)((n13 + 255) / 256);
  const int bw2 = (int)((nw2 + 255) / 256);

  const int nwg1 = (FS / 128) * MT;
  const int nwg2 = (D / 256) * MT;

  if (w13_in_dout) {
    cvt_w13_kernel<<<b13, 256, 0, stream>>>(w1, w3, w13, D, F, FS, 0);
    cvt_w2_kernel<<<bw2, 256, 0, stream>>>(w2, w2s, D, F, FS, 0);
    ffn1_kernel<<<nwg1, 512, 0, stream>>>(xb, w13, routed_token, routed_w, meta, hbuf, D, FS);
    if (use_y) {
      ffn2_kernel<<<nwg2, 512, 0, stream>>>(hbuf, w2s, routed_token, meta, out, ybuf, D, FS);
      combine_kernel<<<(int)N, D / 8, 0, stream>>>(ybuf, slot_pos, out, D);
    } else {
      hipMemsetAsync(out, 0, out_bytes, stream);
      ffn2_kernel<<<nwg2, 512, 0, stream>>>(hbuf, w2s, routed_token, meta, out, nullptr, D, FS);
    }
  } else {
    hipMemsetAsync(out, 0, out_bytes, stream);
    for (int s = 0; s < S; ++s) {
      int fbase = s * FS;
      cvt_w13_kernel<<<b13, 256, 0, stream>>>(w1, w3, w13, D, F, FS, fbase);
      cvt_w2_kernel<<<bw2, 256, 0, stream>>>(w2, w2s, D, F, FS, fbase);
      ffn1_kernel<<<nwg1, 512, 0, stream>>>(xb, w13, routed_token, routed_w, meta, hbuf, D, FS);
      ffn2_kernel<<<nwg2, 512, 0, stream>>>(hbuf, w2s, routed_token, meta, out, nullptr, D, FS);
    }
  }
}